// Round 17
// baseline (284.377 us; speedup 1.0000x reference)
//
#include <hip/hip_runtime.h>
#include <math.h>

#define H   256
#define H2  512
#define MX  16   // max edges kept per node bucket (P(overflow) ~ 4e-10 for Poisson(1))

typedef __attribute__((ext_vector_type(4))) float f32x4;
typedef __attribute__((ext_vector_type(8))) short short8;

// f32 -> bf16 round-to-nearest-even
__device__ __forceinline__ short f2bf(float f) {
  unsigned u = __builtin_bit_cast(unsigned, f);
  u = (u + 0x7FFFu + ((u >> 16) & 1u)) >> 16;
  return (short)u;
}

__device__ __forceinline__ void gload_lds16(const void* g, void* l) {
  __builtin_amdgcn_global_load_lds(
      (const __attribute__((address_space(1))) unsigned int*)g,
      (__attribute__((address_space(3))) unsigned int*)l, 16, 0, 0);
}

// ---- prep: tail-indexed edge buckets + u = W^T attn + Wt bf16 subtiles ----
__global__ void k_prep(const int* __restrict__ ei, const int* __restrict__ cvt,
                       const float* __restrict__ W, const float* __restrict__ attn,
                       unsigned* __restrict__ cnt, int* __restrict__ ebuf,
                       float* __restrict__ u, short* __restrict__ Wt, int E) {
  int g = blockIdx.x * blockDim.x + threadIdx.x;
  if (g < E) {
    int tail = ei[E + g];
    if (cvt[tail]) {
      unsigned pos = atomicAdd(cnt + tail, 1u);
      if (pos < MX) ebuf[(size_t)tail * MX + pos] = g;
    }
  }
  if (g < 512) {
    float s = 0.f;
    for (int h = 0; h < H; ++h) s += W[(size_t)h * H2 + g] * attn[h];
    u[g] = s;
  }
  if (g < 16384) {
    int n = g & 255, kb = g >> 8;
    const float* src = W + (size_t)n * H2 + kb * 8;
    f32x4 a = *(const f32x4*)src;
    f32x4 b = *(const f32x4*)(src + 4);
    short8 o;
    o[0]=f2bf(a.x); o[1]=f2bf(a.y); o[2]=f2bf(a.z); o[3]=f2bf(a.w);
    o[4]=f2bf(b.x); o[5]=f2bf(b.y); o[6]=f2bf(b.z); o[7]=f2bf(b.w);
    *(short8*)(Wt + (size_t)(kb * 256 + n) * 8) = o;
  }
}

// ---- two-region compaction: actpk[0..n2) = c>=2 (node|deg<<20);
//      actc1/eid1c[0..nc1) = c==1 nodes + their single edge id. ----
__global__ void k_slots(const unsigned* __restrict__ cnt, const int* __restrict__ ebuf,
                        int* __restrict__ ctrs, int* __restrict__ actpk,
                        int* __restrict__ actc1, int* __restrict__ eid1c, int N) {
  int n = blockIdx.x * blockDim.x + threadIdx.x;
  int lane = threadIdx.x & 63;
  unsigned c = (n < N) ? cnt[n] : 0u;
  bool is2 = c >= 2u, is1 = c == 1u;
  unsigned long long m2 = __ballot(is2);
  if (m2) {
    int rank = __popcll(m2 & ((1ull << lane) - 1ull));
    int wc = __popcll(m2);
    int base = 0;
    if (lane == 0) base = atomicAdd(ctrs + 0, wc);
    base = __shfl(base, 0);
    if (is2) {
      int cc = (int)(c > MX ? MX : c);
      actpk[base + rank] = n | (cc << 20);
    }
  }
  unsigned long long m1 = __ballot(is1);
  if (m1) {
    int rank = __popcll(m1 & ((1ull << lane) - 1ull));
    int wc = __popcll(m1);
    int base = 0;
    if (lane == 0) base = atomicAdd(ctrs + 1, wc);
    base = __shfl(base, 0);
    if (is1) {
      actc1[base + rank] = n;
      eid1c[base + rank] = ebuf[(size_t)n * MX];
    }
  }
}

// ---- direct-A GEMM for degree-1 nodes: out[n] = concat(R[e],NT[e]) @ Wt^T + sc.
//      64-row tile; A staged as f32 via global_load_lds (2 sub-chunks of 16B
//      per row per k-step), converted to bf16 at fragment read. 48KB LDS. ----
__global__ __launch_bounds__(256) void k_gemmD(
    const float* __restrict__ R, const float* __restrict__ NT,
    const short* __restrict__ Wt, const int* __restrict__ actc1,
    const int* __restrict__ eid1c, const int* __restrict__ ctrs,
    const float* __restrict__ sc, float* __restrict__ out) {
  __shared__ __align__(16) float Asf[2][4][2][64][4];  // 16KB: [buf][kg][sub][row][4f32]
  __shared__ __align__(16) short Bs[2][4][256][8];     // 32KB
  int nc1 = ctrs[1];
  int base = blockIdx.x * 64;
  if (base >= nc1) return;
  int tid = threadIdx.x, wave = tid >> 6, lane = tid & 63;
  int l15 = lane & 15, lg = lane >> 4;

  int r = base + lane; if (r >= nc1) r = nc1 - 1;
  int e = eid1c[r];
  const float* p0 = R + (size_t)e * H;
  const float* p1 = NT + (size_t)e * H;

  auto stage = [&](int b, int kk) {
    const float* ph = (kk < H) ? p0 : p1;   // k-steps never straddle the halves
    int ko = kk & (H - 1);
    gload_lds16(ph + ko + wave * 8,     &Asf[b][wave][0][0][0]);  // lane -> row lane
    gload_lds16(ph + ko + wave * 8 + 4, &Asf[b][wave][1][0][0]);
    int kb = kk >> 3;
    #pragma unroll
    for (int it = 0; it < 4; ++it)
      gload_lds16(Wt + (size_t)(kb + it) * 2048 + (size_t)tid * 8,
                  &Bs[b][it][wave * 64][0]);
  };

  f32x4 acc[4][4];
  #pragma unroll
  for (int i = 0; i < 4; ++i)
    #pragma unroll
    for (int j = 0; j < 4; ++j) acc[i][j] = (f32x4){0.f, 0.f, 0.f, 0.f};

  stage(0, 0);
  __syncthreads();
  int cur = 0;
  for (int t = 0; t < 16; ++t) {
    if (t < 15) stage(cur ^ 1, (t + 1) * 32);
    short8 bf[4];
    #pragma unroll
    for (int ct = 0; ct < 4; ++ct)
      bf[ct] = *(const short8*)&Bs[cur][lg][wave * 64 + ct * 16 + l15][0];
    #pragma unroll
    for (int rt = 0; rt < 4; ++rt) {
      int row = rt * 16 + l15;
      f32x4 fa = *(const f32x4*)&Asf[cur][lg][0][row][0];
      f32x4 fb = *(const f32x4*)&Asf[cur][lg][1][row][0];
      short8 af;
      af[0]=f2bf(fa.x); af[1]=f2bf(fa.y); af[2]=f2bf(fa.z); af[3]=f2bf(fa.w);
      af[4]=f2bf(fb.x); af[5]=f2bf(fb.y); af[6]=f2bf(fb.z); af[7]=f2bf(fb.w);
      #pragma unroll
      for (int ct = 0; ct < 4; ++ct)
        acc[rt][ct] = __builtin_amdgcn_mfma_f32_16x16x32_bf16(af, bf[ct], acc[rt][ct], 0, 0, 0);
    }
    __syncthreads();
    cur ^= 1;
  }

  // epilogue: D row = lg*4+rr (in 16-row sub-tile), col = l15
  #pragma unroll
  for (int rt = 0; rt < 4; ++rt) {
    #pragma unroll
    for (int rr = 0; rr < 4; ++rr) {
      int sD = base + rt * 16 + lg * 4 + rr;
      if (sD >= nc1) continue;
      int n = actc1[sD];
      float* orow = out + (size_t)n * H;
      #pragma unroll
      for (int ct = 0; ct < 4; ++ct) {
        int c = wave * 64 + ct * 16 + l15;
        __builtin_nontemporal_store(acc[rt][ct][rr] + sc[c], orow + c);
      }
    }
  }
}

// ---- fused finish (R15-proven bodies), c>=2 only in gather:
//      outinit: stream inactive rows.  gather: wave/slot, prefetch-1-ahead,
//      c==2 fast path + generic; staged bf16 row -> dense Ast[slot]. ----
__global__ __launch_bounds__(256) void k_fin(
    const float* __restrict__ NT, const int* __restrict__ cvt,
    const unsigned* __restrict__ cnt, const float* __restrict__ sc,
    const float* __restrict__ R, const float* __restrict__ u,
    const int* __restrict__ actpk, const int* __restrict__ ctrs,
    const int* __restrict__ ebuf, short* __restrict__ Ast,
    float* __restrict__ out, int N) {
  int wid = blockIdx.x * 4 + (threadIdx.x >> 6);
  int nw = gridDim.x * 4;
  int lane = threadIdx.x & 63;

  auto outinit = [&]() {
    f32x4 scl = ((const f32x4*)sc)[lane];
    for (int row = wid; row < N; row += nw) {
      int cv = cvt[row];
      if (cv && cnt[row] > 0u) continue;  // gemmD/gemmS write this row
      f32x4 v = cv ? scl : ((const f32x4*)NT)[(size_t)row * 64 + lane];
      ((f32x4*)out)[(size_t)row * 64 + lane] = v;
    }
  };

  auto gather = [&]() {
    int nAct = ctrs[0];   // c>=2 slots only
    int loff = lane * 8;
    const float* src0 = (loff < H) ? (R + loff) : (NT + (loff - H));
    const f32x4* u4 = (const f32x4*)u;
    f32x4 ua = u4[lane * 2], ub = u4[lane * 2 + 1];
    int s = wid;
    if (s >= nAct) return;
    int pk = actpk[s];
    int n = pk & 0xFFFFF, c = pk >> 20;
    int id = (lane < c) ? ebuf[(size_t)n * MX + lane] : 0;
    while (true) {
      int s2 = s + nw;
      int n2 = 0, c2 = 0, id2 = 0;
      if (s2 < nAct) {
        int pk2 = actpk[s2];
        n2 = pk2 & 0xFFFFF; c2 = pk2 >> 20;
        id2 = (lane < c2) ? ebuf[(size_t)n2 * MX + lane] : 0;
      }
      f32x4 x0, x1;
      if (c == 2) {
        int e0 = __shfl(id, 0), e1 = __shfl(id, 1);
        const f32x4* sA = (const f32x4*)(src0 + (size_t)e0 * H);
        const f32x4* sB = (const f32x4*)(src0 + (size_t)e1 * H);
        f32x4 a0 = sA[0], b0 = sA[1], a1 = sB[0], b1 = sB[1];
        float d0 = a0.x*ua.x + a0.y*ua.y + a0.z*ua.z + a0.w*ua.w
                 + b0.x*ub.x + b0.y*ub.y + b0.z*ub.z + b0.w*ub.w;
        float d1 = a1.x*ua.x + a1.y*ua.y + a1.z*ua.z + a1.w*ua.w
                 + b1.x*ub.x + b1.y*ub.y + b1.z*ub.z + b1.w*ub.w;
        #pragma unroll
        for (int off = 32; off > 0; off >>= 1) {
          d0 += __shfl_xor(d0, off);
          d1 += __shfl_xor(d1, off);
        }
        float p0 = __expf(d0), p1 = __expf(d1);  // |logit|<~8: shift-free softmax safe
        float inv = 1.f / (p0 + p1);
        p0 *= inv; p1 *= inv;
        x0 = a0 * p0 + a1 * p1;
        x1 = b0 * p0 + b1 * p1;
      } else {
        x0 = (f32x4){0.f,0.f,0.f,0.f}; x1 = x0;
        float den = 0.f;
        for (int i = 0; i < c; ++i) {
          int e = __shfl(id, i);
          const f32x4* src = (const f32x4*)(src0 + (size_t)e * H);
          f32x4 a = src[0], b = src[1];
          float d = a.x*ua.x + a.y*ua.y + a.z*ua.z + a.w*ua.w
                  + b.x*ub.x + b.y*ub.y + b.z*ub.z + b.w*ub.w;
          #pragma unroll
          for (int off = 32; off > 0; off >>= 1) d += __shfl_xor(d, off);
          float pe = __expf(d);
          den += pe;
          x0 += a * pe;
          x1 += b * pe;
        }
        float inv = 1.f / den;
        x0 *= inv; x1 *= inv;
      }
      short8 o;
      o[0]=f2bf(x0.x); o[1]=f2bf(x0.y); o[2]=f2bf(x0.z); o[3]=f2bf(x0.w);
      o[4]=f2bf(x1.x); o[5]=f2bf(x1.y); o[6]=f2bf(x1.z); o[7]=f2bf(x1.w);
      *(short8*)(Ast + (size_t)s * H2 + loff) = o;  // dense slot-major staging
      if (s2 >= nAct) break;
      s = s2; n = n2; c = c2; id = id2;
    }
  };

  if (wid & 1) { gather(); outinit(); }
  else         { outinit(); gather(); }
}

// ---- staged-A GEMM (c>=2 slots): 128-row tile, dense Ast bf16, dbuf LDS ----
__global__ __launch_bounds__(256) void k_gemmS(
    const short* __restrict__ Wt, const short* __restrict__ Ast,
    const int* __restrict__ actpk, const int* __restrict__ ctrs,
    const float* __restrict__ sc, float* __restrict__ out) {
  __shared__ __align__(16) short Bs[2][4][256][8];  // 32KB
  __shared__ __align__(16) short As[2][4][128][8];  // 16KB
  int nAct = ctrs[0];
  int base = blockIdx.x * 128;
  if (base >= nAct) return;
  int tid = threadIdx.x;
  int wave = tid >> 6, lane = tid & 63;
  int l15 = lane & 15, lg = lane >> 4;

  int row0 = base + lane;       if (row0 >= nAct) row0 = nAct - 1;
  int row1 = base + 64 + lane;  if (row1 >= nAct) row1 = nAct - 1;
  const short* arow0 = Ast + (size_t)row0 * H2;
  const short* arow1 = Ast + (size_t)row1 * H2;

  auto stage = [&](int b, int kk) {
    gload_lds16(arow0 + kk + wave * 8, &As[b][wave][0][0]);
    gload_lds16(arow1 + kk + wave * 8, &As[b][wave][64][0]);
    int kb = kk >> 3;
    #pragma unroll
    for (int it = 0; it < 4; ++it) {
      const short* src = Wt + (size_t)(kb + it) * 2048 + (size_t)tid * 8;
      gload_lds16(src, &Bs[b][it][wave * 64][0]);
    }
  };

  f32x4 acc[8][4];
  #pragma unroll
  for (int i = 0; i < 8; ++i)
    #pragma unroll
    for (int j = 0; j < 4; ++j) acc[i][j] = (f32x4){0.f, 0.f, 0.f, 0.f};

  stage(0, 0);
  __syncthreads();
  int cur = 0;
  for (int t = 0; t < 16; ++t) {
    if (t < 15) stage(cur ^ 1, (t + 1) * 32);
    short8 bf[4];
    #pragma unroll
    for (int ct = 0; ct < 4; ++ct)
      bf[ct] = *(const short8*)&Bs[cur][lg][wave * 64 + ct * 16 + l15][0];
    #pragma unroll
    for (int rt = 0; rt < 8; ++rt) {
      short8 af = *(const short8*)&As[cur][lg][rt * 16 + l15][0];
      #pragma unroll
      for (int ct = 0; ct < 4; ++ct)
        acc[rt][ct] = __builtin_amdgcn_mfma_f32_16x16x32_bf16(af, bf[ct], acc[rt][ct], 0, 0, 0);
    }
    __syncthreads();
    cur ^= 1;
  }

  #pragma unroll
  for (int rt = 0; rt < 8; ++rt) {
    #pragma unroll
    for (int rr = 0; rr < 4; ++rr) {
      int sD = base + rt * 16 + lg * 4 + rr;
      if (sD >= nAct) continue;
      int n = actpk[sD] & 0xFFFFF;
      float* orow = out + (size_t)n * H;
      #pragma unroll
      for (int ct = 0; ct < 4; ++ct) {
        int c = wave * 64 + ct * 16 + l15;
        __builtin_nontemporal_store(acc[rt][ct][rr] + sc[c], orow + c);
      }
    }
  }
}

extern "C" void kernel_launch(void* const* d_in, const int* in_sizes, int n_in,
                              void* d_out, int out_size, void* d_ws, size_t ws_size,
                              hipStream_t stream) {
  const float* NT   = (const float*)d_in[0];
  const float* R    = (const float*)d_in[1];
  const int*   ei   = (const int*)d_in[2];
  const int*   cvt  = (const int*)d_in[3];
  const float* sc   = (const float*)d_in[4];
  const float* attn = (const float*)d_in[5];
  const float* W    = (const float*)d_in[6];
  float* out = (float*)d_out;

  int N = in_sizes[0] / H;
  int E = in_sizes[1] / H;

  char* wsp = (char*)d_ws;
  auto alloc = [&](size_t bytes) { char* r = wsp; wsp += (bytes + 255) & ~(size_t)255; return r; };
  float*    u       = (float*)alloc(512 * 4);
  short*    Wt      = (short*)alloc((size_t)H * H2 * 2);
  int*      ebuf    = (int*)alloc((size_t)N * MX * 4);
  short*    Ast     = (short*)alloc((size_t)N * H2 * 2);  // dense staged A rows (c>=2)
  unsigned* cnt     = (unsigned*)alloc((size_t)N * 4);
  int*      actpk   = (int*)alloc((size_t)N * 4);
  int*      actc1   = (int*)alloc((size_t)N * 4);
  int*      eid1c   = (int*)alloc((size_t)N * 4);
  int*      ctrs    = (int*)alloc(2 * 4);

  hipMemsetAsync(cnt, 0, (size_t)N * 4, stream);
  hipMemsetAsync(ctrs, 0, 8, stream);
  k_prep<<<(E + 255) / 256, 256, 0, stream>>>(ei, cvt, W, attn, cnt, ebuf, u, Wt, E);
  k_slots<<<(N + 255) / 256, 256, 0, stream>>>(cnt, ebuf, ctrs, actpk, actc1, eid1c, N);
  k_gemmD<<<(N + 63) / 64, 256, 0, stream>>>(R, NT, Wt, actc1, eid1c, ctrs, sc, out);
  k_fin<<<2048, 256, 0, stream>>>(NT, cvt, cnt, sc, R, u, actpk, ctrs, ebuf, Ast, out, N);
  k_gemmS<<<(N + 127) / 128, 256, 0, stream>>>(Wt, Ast, actpk, ctrs, sc, out);
}